// Round 16
// baseline (103.268 us; speedup 1.0000x reference)
//
#include <hip/hip_runtime.h>
#include <hip/hip_fp16.h>

#define CUT_SIZE 224
#define SIDE 1024
#define CUTN 128
#define NSLAB 8
#define SLAB_BLOCKS 192                 // 8*192 = 1536 blocks = 6/CU @ 24.8 KB LDS (co-resident)
#define LDSW2 1032                      // halves per channel row (max needed 1027) + slack

// d_ws (uint32 words): A[8][128] | B[8][128] rlo | TOT[8] | CNT[8] (64B-spaced)
#define WS_A     0
#define WS_B     (NSLAB * CUTN)
#define WS_TOT   (2 * NSLAB * CUTN)
#define WS_CNT   (2 * NSLAB * CUTN + NSLAB)
#define WS_WORDS (WS_CNT + NSLAB * 16)

// ---------- plan: weighted equal-work slab quantiles + queue reset ----------
__global__ __launch_bounds__(256) void plan_kernel(
    const int* __restrict__ sizes, const int* __restrict__ offy,
    unsigned int* __restrict__ ws)
{
    __shared__ float s_inv[CUTN], s_oy[CUTN];
    __shared__ int   s_wt[CUTN];
    __shared__ int   cdf[129];
    __shared__ int   qb[NSLAB + 1];
    __shared__ unsigned short slen[NSLAB][CUTN];
    const int t = threadIdx.x;

    if (t < CUTN) {
        const int sz = sizes[t];
        s_inv[t] = (float)CUT_SIZE / (float)sz;
        s_oy[t]  = (float)offy[t];
        s_wt[t]  = 100 + (sz >> 2);     // cost model: fixed(~600cy) + staging ~ sz
    }
    if (t < NSLAB) ws[WS_CNT + t * 16] = 0u;   // reset dynamic queues EVERY launch
    __syncthreads();

    for (int k = t; k <= 128; k += 256) {
        const float Yf = (float)(k << 3);
        int c = 0;
        for (int n = 0; n < CUTN; ++n) {
            const float thr = (Yf + 0.5f - s_oy[n]) * s_inv[n] - 0.5f;
            c += min(CUT_SIZE, max(0, (int)ceilf(thr))) * s_wt[n];
        }
        cdf[k] = c;
    }
    __syncthreads();

    if (t >= 1 && t < NSLAB) {
        const long long target = (long long)t * (long long)cdf[128] / NSLAB;
        int lo = 0, hi = 128;
        while (hi - lo > 1) { const int m = (lo + hi) >> 1;
                              if ((long long)cdf[m] >= target) hi = m; else lo = m; }
        qb[t] = hi << 3;
    }
    if (t == 0) { qb[0] = 0; qb[NSLAB] = SIDE; }
    __syncthreads();

    for (int idx = t; idx < NSLAB * CUTN; idx += 256) {
        const int s = idx >> 7, n = idx & (CUTN - 1);
        int rlo, rhi;
        { const int Y = qb[s];
          rlo = (Y <= 0) ? 0
              : min(CUT_SIZE, max(0, (int)ceilf(((float)Y + 0.5f - s_oy[n]) * s_inv[n] - 0.5f))); }
        { const int Y = qb[s + 1];
          rhi = (Y >= SIDE) ? CUT_SIZE
              : min(CUT_SIZE, max(0, (int)ceilf(((float)Y + 0.5f - s_oy[n]) * s_inv[n] - 0.5f))); }
        slen[s][n] = (unsigned short)(rhi - rlo);
        ws[WS_B + idx] = (unsigned)rlo;
    }
    __syncthreads();

    if (t < NSLAB) {
        unsigned run = 0;
        for (int n = 0; n < CUTN; ++n) {
            ws[WS_A + t * CUTN + n] = run;
            run += slen[t][n];
        }
        ws[WS_TOT + t] = run;
    }
}

// ---------- main: r13 row-task body + dynamic per-slab task queue ----------
__global__ __launch_bounds__(256) void cutout_row_kernel(
    const float* __restrict__ img,     // [3, 1024, 1024]
    const int* __restrict__ sizes,
    const int* __restrict__ offy,
    const int* __restrict__ offx,
    unsigned int* __restrict__ ws,
    float* __restrict__ out)           // [128, 3, 224, 224]
{
    __shared__ __half lds[4][3][LDSW2];             // 24.8 KB: wave-private 3-ch blended rows
    const int s    = blockIdx.x & 7;                // slab == XCD (co-resident grid)
    const int w    = threadIdx.x >> 6;
    const int lane = threadIdx.x & 63;

    const unsigned* __restrict__ A = ws + WS_A + s * CUTN;
    const unsigned* __restrict__ B = ws + WS_B + s * CUTN;
    const unsigned T = ws[WS_TOT + s];
    unsigned int* __restrict__ cnt = ws + WS_CNT + s * 16;   // own 64B line, own XCD L2
    __half* __restrict__ l0 = &lds[w][0][0];
    __half* __restrict__ l1 = &lds[w][1][0];
    __half* __restrict__ l2 = &lds[w][2][0];

    // Preload ALL decode tables into registers (two 64-entry halves per table,
    // accessed via __shfl). 10 one-time loads; zero per-task global meta loads.
    const unsigned aLo = A[lane],            aHi = A[64 + lane];
    const unsigned bLo = B[lane],            bHi = B[64 + lane];
    const float   szLo = (float)sizes[lane], szHi = (float)sizes[64 + lane];
    const float   oyLo = (float)offy[lane],  oyHi = (float)offy[64 + lane];
    const float   oxLo = (float)offx[lane],  oxHi = (float)offx[64 + lane];

    // dynamic pop: one atomic per wave per task; output is task-deterministic
    auto pop = [&]() -> unsigned {
        unsigned v = 0;
        if (lane == 0) v = atomicAdd(cnt, 1u);
        return (unsigned)__shfl((int)v, 0);
    };

    for (unsigned i = pop(); i < T; i = pop()) {
        // bit-descend bsearch over A via lane shuffles: max n with A[n] <= i.
        int n = 0;
        unsigned An = 0;                             // A[0] == 0
#pragma unroll
        for (int st = 64; st; st >>= 1) {
            const int m = n | st;                    // <= 127
            const unsigned Am = (m & 64) ? (unsigned)__shfl((int)aHi, m & 63)
                                         : (unsigned)__shfl((int)aLo, m & 63);
            if (Am <= i) { n = m; An = Am; }
        }
        const int hi6 = n & 64, lo6 = n & 63;
        const unsigned rlo = hi6 ? (unsigned)__shfl((int)bHi, lo6)
                                 : (unsigned)__shfl((int)bLo, lo6);
        const int   y  = (int)rlo + (int)(i - An);
        const float sz = hi6 ? __shfl(szHi, lo6) : __shfl(szLo, lo6);
        const float oy = hi6 ? __shfl(oyHi, lo6) : __shfl(oyLo, lo6);
        const float ox = hi6 ? __shfl(oxHi, lo6) : __shfl(oxLo, lo6);

        const float scale = sz * (1.0f / (float)CUT_SIZE);

        float fy = fmaf((float)y + 0.5f, scale, oy - 0.5f);
        fy = fminf(fmaxf(fy, 0.0f), (float)(SIDE - 1));
        const int   y0 = (int)fy;
        const int   y1 = min(y0 + 1, SIDE - 1);
        const float wy  = fy - (float)y0;
        const float wy0 = 1.0f - wy;

        // x span (wave-uniform per cutout)
        float fx0 = fmaf(0.5f, scale, ox - 0.5f);
        fx0 = fminf(fmaxf(fx0, 0.0f), (float)(SIDE - 1));
        float fxl = fmaf((float)CUT_SIZE - 0.5f, scale, ox - 0.5f);
        fxl = fminf(fmaxf(fxl, 0.0f), (float)(SIDE - 1));
        const int xb    = (int)fx0;
        const int xe    = min((int)fxl + 1, SIDE - 1);
        const int xb4   = xb & ~3;                  // 16B-aligned load base
        const int ilast = xe - xb4;
        const int nf4   = (ilast >> 2) + 1;         // wave-uniform float4 count (<=257)

        const size_t cstride = (size_t)SIDE * SIDE;
        const float* b0 = img + (size_t)y0 * SIDE + xb4;
        const float* b1 = img + (size_t)y1 * SIDE + xb4;
        const float4* __restrict__ rp0 = reinterpret_cast<const float4*>(b0);
        const float4* __restrict__ rq0 = reinterpret_cast<const float4*>(b1);
        const float4* __restrict__ rp1 = reinterpret_cast<const float4*>(b0 + cstride);
        const float4* __restrict__ rq1 = reinterpret_cast<const float4*>(b1 + cstride);
        const float4* __restrict__ rp2 = reinterpret_cast<const float4*>(b0 + 2 * cstride);
        const float4* __restrict__ rq2 = reinterpret_cast<const float4*>(b1 + 2 * cstride);

        // Stage all 3 channels: 6 independent L2-local float4 loads per iter.
        // Last load base col = xb4+4(nf4-1) <= xe <= 1023, 4-aligned: never OOB.
        for (int k = lane; k < nf4; k += 64) {
            const float4 a0 = rp0[k], c0 = rq0[k];
            const float4 a1 = rp1[k], c1 = rq1[k];
            const float4 a2 = rp2[k], c2 = rq2[k];
            union { __half2 h[2]; uint2 u; } pk;
            pk.h[0] = __floats2half2_rn(a0.x * wy0 + c0.x * wy, a0.y * wy0 + c0.y * wy);
            pk.h[1] = __floats2half2_rn(a0.z * wy0 + c0.z * wy, a0.w * wy0 + c0.w * wy);
            *reinterpret_cast<uint2*>(l0 + 4 * k) = pk.u;
            pk.h[0] = __floats2half2_rn(a1.x * wy0 + c1.x * wy, a1.y * wy0 + c1.y * wy);
            pk.h[1] = __floats2half2_rn(a1.z * wy0 + c1.z * wy, a1.w * wy0 + c1.w * wy);
            *reinterpret_cast<uint2*>(l1 + 4 * k) = pk.u;
            pk.h[0] = __floats2half2_rn(a2.x * wy0 + c2.x * wy, a2.y * wy0 + c2.y * wy);
            pk.h[1] = __floats2half2_rn(a2.z * wy0 + c2.z * wy, a2.w * wy0 + c2.w * wy);
            *reinterpret_cast<uint2*>(l2 + 4 * k) = pk.u;
        }
        // Pad zero at ilast+1 (read only when wx==0; avoids stale-LDS NaN*0).
        if (lane < 3) (&lds[w][lane][0])[ilast + 1] = __float2half(0.0f);
        // Wave-private LDS: one drain per task; "memory" stops reordering.
        asm volatile("s_waitcnt lgkmcnt(0)" ::: "memory");

        // Gather: 4 consecutive px per lane (lanes 0..55), one float4 store/channel.
        const int p0 = lane << 2;
        if (p0 < CUT_SIZE) {
            const float xb4f = (float)xb4;
            float fx = fmaf((float)p0 + 0.5f, scale, ox - 0.5f);
            float4 o0, o1, o2;
            float* v0 = &o0.x; float* v1 = &o1.x; float* v2 = &o2.x;
#pragma unroll
            for (int j = 0; j < 4; ++j) {
                const float fxj = fminf(fmaxf(fx, 0.0f), (float)(SIDE - 1));
                fx += scale;                         // incremental column coordinate
                const float fl = fxj - xb4f;         // >= 0, <= ilast
                const int   i0 = (int)fl;
                const float wx  = fl - (float)i0;
                const float wx0 = 1.0f - wx;
                v0[j] = fminf(fmaxf(__half2float(l0[i0]) * wx0 + __half2float(l0[i0 + 1]) * wx, 0.0f), 1.0f);
                v1[j] = fminf(fmaxf(__half2float(l1[i0]) * wx0 + __half2float(l1[i0 + 1]) * wx, 0.0f), 1.0f);
                v2[j] = fminf(fmaxf(__half2float(l2[i0]) * wx0 + __half2float(l2[i0 + 1]) * wx, 0.0f), 1.0f);
            }
            const size_t obase = (((size_t)n * 3) * CUT_SIZE + y) * CUT_SIZE + p0;
            *reinterpret_cast<float4*>(out + obase) = o0;
            *reinterpret_cast<float4*>(out + obase + CUT_SIZE * CUT_SIZE) = o1;
            *reinterpret_cast<float4*>(out + obase + 2 * (CUT_SIZE * CUT_SIZE)) = o2;
        }
        // Next task's ds_writes must not be hoisted past these ds_reads.
        asm volatile("" ::: "memory");
    }
}

// ---------- fallback (only if ws too small; known-correct round-3 structure) ----------
__global__ __launch_bounds__(128) void make_cutouts_fallback(
    const float* __restrict__ img, const int* __restrict__ sizes,
    const int* __restrict__ offy, const int* __restrict__ offx,
    float* __restrict__ out)
{
    __shared__ float lds[2][1032];
    const int n    = blockIdx.y;
    const int w    = threadIdx.x >> 6;
    const int lane = threadIdx.x & 63;
    const int y    = blockIdx.x * 2 + w;
    const float scale = (float)sizes[n] * (1.0f / (float)CUT_SIZE);
    const float oy = (float)offy[n];
    const float ox = (float)offx[n];
    float fy = fmaf((float)y + 0.5f, scale, oy - 0.5f);
    fy = fminf(fmaxf(fy, 0.0f), (float)(SIDE - 1));
    const int y0 = (int)fy, y1 = min(y0 + 1, SIDE - 1);
    const float wy = fy - (float)y0, wy0 = 1.0f - wy;
    float fx0 = fmaf(0.5f, scale, ox - 0.5f);
    fx0 = fminf(fmaxf(fx0, 0.0f), (float)(SIDE - 1));
    float fxl = fmaf((float)CUT_SIZE - 0.5f, scale, ox - 0.5f);
    fxl = fminf(fmaxf(fxl, 0.0f), (float)(SIDE - 1));
    const int xb = (int)fx0, xe = min((int)fxl + 1, SIDE - 1);
    const int xb4 = xb & ~3, ilast = xe - xb4, nf4 = (ilast >> 2) + 1;
    int i0r[4], i1r[4]; float wxr[4], wx0r[4];
#pragma unroll
    for (int it = 0; it < 4; ++it) {
        const int p = min(lane + it * 64, CUT_SIZE - 1);
        float fx = fmaf((float)p + 0.5f, scale, ox - 0.5f);
        fx = fminf(fmaxf(fx, 0.0f), (float)(SIDE - 1));
        const float fl = fx - (float)xb4;
        const int i0 = (int)fl;
        i0r[it] = i0; i1r[it] = min(i0 + 1, ilast);
        wxr[it] = fl - (float)i0; wx0r[it] = 1.0f - wxr[it];
    }
    const int r0off = y0 * SIDE + xb4, r1off = y1 * SIDE + xb4;
    float* __restrict__ l = lds[w];
    const size_t obase0 = (((size_t)n * 3) * CUT_SIZE + y) * CUT_SIZE;
    for (int c = 0; c < 3; ++c) {
        const float* __restrict__ ch = img + (size_t)c * (SIDE * SIDE);
        const float4* __restrict__ rp0 = reinterpret_cast<const float4*>(ch + r0off);
        const float4* __restrict__ rp1 = reinterpret_cast<const float4*>(ch + r1off);
        for (int k = lane; k < nf4; k += 64) {
            const float4 a = rp0[k]; const float4 b = rp1[k];
            float4 r;
            r.x = a.x * wy0 + b.x * wy; r.y = a.y * wy0 + b.y * wy;
            r.z = a.z * wy0 + b.z * wy; r.w = a.w * wy0 + b.w * wy;
            *reinterpret_cast<float4*>(l + 4 * k) = r;
        }
        asm volatile("s_waitcnt lgkmcnt(0)" ::: "memory");
        const size_t obase = obase0 + (size_t)c * (CUT_SIZE * CUT_SIZE);
#pragma unroll
        for (int it = 0; it < 4; ++it) {
            const int p = lane + it * 64;
            if (p < CUT_SIZE) {
                float v = l[i0r[it]] * wx0r[it] + l[i1r[it]] * wxr[it];
                v = fminf(fmaxf(v, 0.0f), 1.0f);
                out[obase + p] = v;
            }
        }
        asm volatile("" ::: "memory");
    }
}

extern "C" void kernel_launch(void* const* d_in, const int* in_sizes, int n_in,
                              void* d_out, int out_size, void* d_ws, size_t ws_size,
                              hipStream_t stream) {
    const float* img   = (const float*)d_in[0];
    const int*   sizes = (const int*)d_in[1];
    const int*   offy  = (const int*)d_in[2];
    const int*   offx  = (const int*)d_in[3];
    float*       out   = (float*)d_out;

    if (ws_size >= (size_t)WS_WORDS * 4) {
        unsigned int* ws = (unsigned int*)d_ws;
        plan_kernel<<<1, 256, 0, stream>>>(sizes, offy, ws);
        cutout_row_kernel<<<NSLAB * SLAB_BLOCKS, 256, 0, stream>>>(
            img, sizes, offy, offx, ws, out);
    } else {
        make_cutouts_fallback<<<dim3(CUT_SIZE / 2, CUTN), 128, 0, stream>>>(
            img, sizes, offy, offx, out);
    }
}

// Round 17
// 41.661 us; speedup vs baseline: 2.4788x; 2.4788x over previous
//
#include <hip/hip_runtime.h>
#include <hip/hip_fp16.h>

#define CUT_SIZE 224
#define SIDE 1024
#define CUTN 128
#define NSLAB 8
#define SLAB_BLOCKS 192                 // 8*192 = 1536 blocks = 6/CU @ 24.8 KB LDS (co-resident)
#define SLAB_WSLOTS (SLAB_BLOCKS * 4)   // 768 wave slots per slab
#define LDSW2 1032                      // halves per channel row (max needed 1027) + slack

// d_ws (uint32 words): A[8][128] | B[8][128] rlo | WC[8][128] cost-prefix | TOT[8] | WT[8]
#define WS_A     0
#define WS_B     (NSLAB * CUTN)
#define WS_WC    (2 * NSLAB * CUTN)
#define WS_TOT   (3 * NSLAB * CUTN)
#define WS_WT    (3 * NSLAB * CUTN + NSLAB)
#define WS_WORDS (3 * NSLAB * CUTN + 2 * NSLAB)

// cost model per output row of cutout n (MUST match main kernel's wt())
__device__ __forceinline__ int row_cost(int sz) { return 100 + (sz >> 2); }

// ---------- plan: weighted equal-work slab quantiles + cost prefixes ----------
__global__ __launch_bounds__(256) void plan_kernel(
    const int* __restrict__ sizes, const int* __restrict__ offy,
    unsigned int* __restrict__ ws)
{
    __shared__ float s_inv[CUTN], s_oy[CUTN];
    __shared__ int   s_wt[CUTN];
    __shared__ int   cdf[129];
    __shared__ int   qb[NSLAB + 1];
    __shared__ unsigned short slen[NSLAB][CUTN];
    const int t = threadIdx.x;

    if (t < CUTN) {
        const int sz = sizes[t];
        s_inv[t] = (float)CUT_SIZE / (float)sz;
        s_oy[t]  = (float)offy[t];
        s_wt[t]  = row_cost(sz);
    }
    __syncthreads();

    for (int k = t; k <= 128; k += 256) {
        const float Yf = (float)(k << 3);
        int c = 0;
        for (int n = 0; n < CUTN; ++n) {
            const float thr = (Yf + 0.5f - s_oy[n]) * s_inv[n] - 0.5f;
            c += min(CUT_SIZE, max(0, (int)ceilf(thr))) * s_wt[n];
        }
        cdf[k] = c;
    }
    __syncthreads();

    if (t >= 1 && t < NSLAB) {
        const long long target = (long long)t * (long long)cdf[128] / NSLAB;
        int lo = 0, hi = 128;
        while (hi - lo > 1) { const int m = (lo + hi) >> 1;
                              if ((long long)cdf[m] >= target) hi = m; else lo = m; }
        qb[t] = hi << 3;
    }
    if (t == 0) { qb[0] = 0; qb[NSLAB] = SIDE; }
    __syncthreads();

    for (int idx = t; idx < NSLAB * CUTN; idx += 256) {
        const int s = idx >> 7, n = idx & (CUTN - 1);
        int rlo, rhi;
        { const int Y = qb[s];
          rlo = (Y <= 0) ? 0
              : min(CUT_SIZE, max(0, (int)ceilf(((float)Y + 0.5f - s_oy[n]) * s_inv[n] - 0.5f))); }
        { const int Y = qb[s + 1];
          rhi = (Y >= SIDE) ? CUT_SIZE
              : min(CUT_SIZE, max(0, (int)ceilf(((float)Y + 0.5f - s_oy[n]) * s_inv[n] - 0.5f))); }
        slen[s][n] = (unsigned short)(rhi - rlo);
        ws[WS_B + idx] = (unsigned)rlo;
    }
    __syncthreads();

    if (t < NSLAB) {                    // serial prefixes: tasks (A) and cost (WC)
        unsigned run = 0, wrun = 0;
        for (int n = 0; n < CUTN; ++n) {
            ws[WS_A  + t * CUTN + n] = run;
            ws[WS_WC + t * CUTN + n] = wrun;
            run  += slen[t][n];
            wrun += (unsigned)slen[t][n] * (unsigned)s_wt[n];
        }
        ws[WS_TOT + t] = run;
        ws[WS_WT  + t] = wrun;
    }
}

// ---------- main: r13 body + static cost-balanced contiguous wave ranges ----------
__global__ __launch_bounds__(256) void cutout_row_kernel(
    const float* __restrict__ img,     // [3, 1024, 1024]
    const int* __restrict__ sizes,
    const int* __restrict__ offy,
    const int* __restrict__ offx,
    const unsigned int* __restrict__ ws,
    float* __restrict__ out)           // [128, 3, 224, 224]
{
    __shared__ __half lds[4][3][LDSW2];             // 24.8 KB: wave-private 3-ch blended rows
    const int s    = blockIdx.x & 7;                // slab == XCD (co-resident grid)
    const int w    = threadIdx.x >> 6;
    const int lane = threadIdx.x & 63;
    const unsigned q = (unsigned)(blockIdx.x >> 3) * 4u + (unsigned)w;  // 0..767

    const unsigned* __restrict__ A = ws + WS_A + s * CUTN;
    const unsigned* __restrict__ B = ws + WS_B + s * CUTN;
    const unsigned* __restrict__ WC = ws + WS_WC + s * CUTN;
    const unsigned T = ws[WS_TOT + s];
    const unsigned long long WT = (unsigned long long)ws[WS_WT + s];
    __half* __restrict__ l0 = &lds[w][0][0];
    __half* __restrict__ l1 = &lds[w][1][0];
    __half* __restrict__ l2 = &lds[w][2][0];

    // Register-resident decode tables (two 64-entry halves, __shfl access).
    const unsigned aLo = A[lane],             aHi = A[64 + lane];
    const unsigned bLo = B[lane],             bHi = B[64 + lane];
    const unsigned wcLo = WC[lane],           wcHi = WC[64 + lane];
    const float   szLo = (float)sizes[lane],  szHi = (float)sizes[64 + lane];
    const float   oyLo = (float)offy[lane],   oyHi = (float)offy[64 + lane];
    const float   oxLo = (float)offx[lane],   oxHi = (float)offx[64 + lane];

    auto shA  = [&](int m) -> unsigned {
        return (m & 64) ? (unsigned)__shfl((int)aHi, m & 63) : (unsigned)__shfl((int)aLo, m & 63); };
    auto shB  = [&](int m) -> unsigned {
        return (m & 64) ? (unsigned)__shfl((int)bHi, m & 63) : (unsigned)__shfl((int)bLo, m & 63); };
    auto shWC = [&](int m) -> unsigned {
        return (m & 64) ? (unsigned)__shfl((int)wcHi, m & 63) : (unsigned)__shfl((int)wcLo, m & 63); };
    auto shSZ = [&](int m) -> float {
        return (m & 64) ? __shfl(szHi, m & 63) : __shfl(szLo, m & 63); };
    auto shOY = [&](int m) -> float {
        return (m & 64) ? __shfl(oyHi, m & 63) : __shfl(oyLo, m & 63); };
    auto shOX = [&](int m) -> float {
        return (m & 64) ? __shfl(oxHi, m & 63) : __shfl(oxLo, m & 63); };

    // invert cost quantile -> (cutout n, task index i); monotone in tgt => exact partition
    auto locate = [&](unsigned long long tgt, int& n_out) -> unsigned {
        int n = 0; unsigned Wn = 0;
#pragma unroll
        for (int st = 64; st; st >>= 1) {
            const int m = n | st;                       // <= 127
            const unsigned Wm = shWC(m);
            if ((unsigned long long)Wm <= tgt) { n = m; Wn = Wm; }
        }
        const unsigned wt = 100u + (((unsigned)shSZ(n)) >> 2);   // == row_cost
        const unsigned r  = (unsigned)(tgt - Wn) / wt;
        n_out = n;
        return shA(n) + r;
    };

    int n;                                              // current cutout
    unsigned i = locate(((unsigned long long)q * WT) / SLAB_WSLOTS, n);
    int nEndDummy;
    const unsigned iEnd = (q + 1 == SLAB_WSLOTS) ? T
        : locate(((unsigned long long)(q + 1) * WT) / SLAB_WSLOTS, nEndDummy);

    if (i < iEnd) {
        unsigned An1 = (n == 127) ? T : shA(n + 1);
        float sz = shSZ(n), oy = shOY(n), ox = shOX(n);
        int   y  = (int)shB(n) + (int)(i - shA(n));
        float scale = sz * (1.0f / (float)CUT_SIZE);

        for (; i < iEnd; ++i) {
            if (i >= An1) {                             // advance to next non-empty cutout
                do { ++n; An1 = (n == 127) ? T : shA(n + 1); } while (An1 <= i);
                sz = shSZ(n); oy = shOY(n); ox = shOX(n);
                y  = (int)shB(n);
                scale = sz * (1.0f / (float)CUT_SIZE);
            }

            float fy = fmaf((float)y + 0.5f, scale, oy - 0.5f);
            fy = fminf(fmaxf(fy, 0.0f), (float)(SIDE - 1));
            const int   y0 = (int)fy;
            const int   y1 = min(y0 + 1, SIDE - 1);
            const float wy  = fy - (float)y0;
            const float wy0 = 1.0f - wy;

            float fx0 = fmaf(0.5f, scale, ox - 0.5f);
            fx0 = fminf(fmaxf(fx0, 0.0f), (float)(SIDE - 1));
            float fxl = fmaf((float)CUT_SIZE - 0.5f, scale, ox - 0.5f);
            fxl = fminf(fmaxf(fxl, 0.0f), (float)(SIDE - 1));
            const int xb    = (int)fx0;
            const int xe    = min((int)fxl + 1, SIDE - 1);
            const int xb4   = xb & ~3;                  // 16B-aligned load base
            const int ilast = xe - xb4;
            const int nf4   = (ilast >> 2) + 1;         // wave-uniform float4 count

            const size_t cstride = (size_t)SIDE * SIDE;
            const float* b0 = img + (size_t)y0 * SIDE + xb4;
            const float* b1 = img + (size_t)y1 * SIDE + xb4;
            const float4* __restrict__ rp0 = reinterpret_cast<const float4*>(b0);
            const float4* __restrict__ rq0 = reinterpret_cast<const float4*>(b1);
            const float4* __restrict__ rp1 = reinterpret_cast<const float4*>(b0 + cstride);
            const float4* __restrict__ rq1 = reinterpret_cast<const float4*>(b1 + cstride);
            const float4* __restrict__ rp2 = reinterpret_cast<const float4*>(b0 + 2 * cstride);
            const float4* __restrict__ rq2 = reinterpret_cast<const float4*>(b1 + 2 * cstride);

            // Stage all 3 channels: 6 independent L2-local float4 loads per iter.
            for (int k = lane; k < nf4; k += 64) {
                const float4 a0 = rp0[k], c0 = rq0[k];
                const float4 a1 = rp1[k], c1 = rq1[k];
                const float4 a2 = rp2[k], c2 = rq2[k];
                union { __half2 h[2]; uint2 u; } pk;
                pk.h[0] = __floats2half2_rn(a0.x * wy0 + c0.x * wy, a0.y * wy0 + c0.y * wy);
                pk.h[1] = __floats2half2_rn(a0.z * wy0 + c0.z * wy, a0.w * wy0 + c0.w * wy);
                *reinterpret_cast<uint2*>(l0 + 4 * k) = pk.u;
                pk.h[0] = __floats2half2_rn(a1.x * wy0 + c1.x * wy, a1.y * wy0 + c1.y * wy);
                pk.h[1] = __floats2half2_rn(a1.z * wy0 + c1.z * wy, a1.w * wy0 + c1.w * wy);
                *reinterpret_cast<uint2*>(l1 + 4 * k) = pk.u;
                pk.h[0] = __floats2half2_rn(a2.x * wy0 + c2.x * wy, a2.y * wy0 + c2.y * wy);
                pk.h[1] = __floats2half2_rn(a2.z * wy0 + c2.z * wy, a2.w * wy0 + c2.w * wy);
                *reinterpret_cast<uint2*>(l2 + 4 * k) = pk.u;
            }
            // Pad zero at ilast+1 (read only when wx==0; avoids stale-LDS NaN*0).
            if (lane < 3) (&lds[w][lane][0])[ilast + 1] = __float2half(0.0f);
            // Wave-private LDS: one drain per task; "memory" stops reordering.
            asm volatile("s_waitcnt lgkmcnt(0)" ::: "memory");

            // Gather: 4 consecutive px per lane (lanes 0..55), float4 store/channel.
            const int p0 = lane << 2;
            if (p0 < CUT_SIZE) {
                const float xb4f = (float)xb4;
                float fx = fmaf((float)p0 + 0.5f, scale, ox - 0.5f);
                float4 o0, o1, o2;
                float* v0 = &o0.x; float* v1 = &o1.x; float* v2 = &o2.x;
#pragma unroll
                for (int j = 0; j < 4; ++j) {
                    const float fxj = fminf(fmaxf(fx, 0.0f), (float)(SIDE - 1));
                    fx += scale;
                    const float fl = fxj - xb4f;
                    const int   i0 = (int)fl;
                    const float wx  = fl - (float)i0;
                    const float wx0 = 1.0f - wx;
                    v0[j] = fminf(fmaxf(__half2float(l0[i0]) * wx0 + __half2float(l0[i0 + 1]) * wx, 0.0f), 1.0f);
                    v1[j] = fminf(fmaxf(__half2float(l1[i0]) * wx0 + __half2float(l1[i0 + 1]) * wx, 0.0f), 1.0f);
                    v2[j] = fminf(fmaxf(__half2float(l2[i0]) * wx0 + __half2float(l2[i0 + 1]) * wx, 0.0f), 1.0f);
                }
                const size_t obase = (((size_t)n * 3) * CUT_SIZE + y) * CUT_SIZE + p0;
                *reinterpret_cast<float4*>(out + obase) = o0;
                *reinterpret_cast<float4*>(out + obase + CUT_SIZE * CUT_SIZE) = o1;
                *reinterpret_cast<float4*>(out + obase + 2 * (CUT_SIZE * CUT_SIZE)) = o2;
            }
            asm volatile("" ::: "memory");
            ++y;                                        // contiguous walk
        }
    }
}

// ---------- fallback (only if ws too small; known-correct round-3 structure) ----------
__global__ __launch_bounds__(128) void make_cutouts_fallback(
    const float* __restrict__ img, const int* __restrict__ sizes,
    const int* __restrict__ offy, const int* __restrict__ offx,
    float* __restrict__ out)
{
    __shared__ float lds[2][1032];
    const int n    = blockIdx.y;
    const int w    = threadIdx.x >> 6;
    const int lane = threadIdx.x & 63;
    const int y    = blockIdx.x * 2 + w;
    const float scale = (float)sizes[n] * (1.0f / (float)CUT_SIZE);
    const float oy = (float)offy[n];
    const float ox = (float)offx[n];
    float fy = fmaf((float)y + 0.5f, scale, oy - 0.5f);
    fy = fminf(fmaxf(fy, 0.0f), (float)(SIDE - 1));
    const int y0 = (int)fy, y1 = min(y0 + 1, SIDE - 1);
    const float wy = fy - (float)y0, wy0 = 1.0f - wy;
    float fx0 = fmaf(0.5f, scale, ox - 0.5f);
    fx0 = fminf(fmaxf(fx0, 0.0f), (float)(SIDE - 1));
    float fxl = fmaf((float)CUT_SIZE - 0.5f, scale, ox - 0.5f);
    fxl = fminf(fmaxf(fxl, 0.0f), (float)(SIDE - 1));
    const int xb = (int)fx0, xe = min((int)fxl + 1, SIDE - 1);
    const int xb4 = xb & ~3, ilast = xe - xb4, nf4 = (ilast >> 2) + 1;
    int i0r[4], i1r[4]; float wxr[4], wx0r[4];
#pragma unroll
    for (int it = 0; it < 4; ++it) {
        const int p = min(lane + it * 64, CUT_SIZE - 1);
        float fx = fmaf((float)p + 0.5f, scale, ox - 0.5f);
        fx = fminf(fmaxf(fx, 0.0f), (float)(SIDE - 1));
        const float fl = fx - (float)xb4;
        const int i0 = (int)fl;
        i0r[it] = i0; i1r[it] = min(i0 + 1, ilast);
        wxr[it] = fl - (float)i0; wx0r[it] = 1.0f - wxr[it];
    }
    const int r0off = y0 * SIDE + xb4, r1off = y1 * SIDE + xb4;
    float* __restrict__ l = lds[w];
    const size_t obase0 = (((size_t)n * 3) * CUT_SIZE + y) * CUT_SIZE;
    for (int c = 0; c < 3; ++c) {
        const float* __restrict__ ch = img + (size_t)c * (SIDE * SIDE);
        const float4* __restrict__ rp0 = reinterpret_cast<const float4*>(ch + r0off);
        const float4* __restrict__ rp1 = reinterpret_cast<const float4*>(ch + r1off);
        for (int k = lane; k < nf4; k += 64) {
            const float4 a = rp0[k]; const float4 b = rp1[k];
            float4 r;
            r.x = a.x * wy0 + b.x * wy; r.y = a.y * wy0 + b.y * wy;
            r.z = a.z * wy0 + b.z * wy; r.w = a.w * wy0 + b.w * wy;
            *reinterpret_cast<float4*>(l + 4 * k) = r;
        }
        asm volatile("s_waitcnt lgkmcnt(0)" ::: "memory");
        const size_t obase = obase0 + (size_t)c * (CUT_SIZE * CUT_SIZE);
#pragma unroll
        for (int it = 0; it < 4; ++it) {
            const int p = lane + it * 64;
            if (p < CUT_SIZE) {
                float v = l[i0r[it]] * wx0r[it] + l[i1r[it]] * wxr[it];
                v = fminf(fmaxf(v, 0.0f), 1.0f);
                out[obase + p] = v;
            }
        }
        asm volatile("" ::: "memory");
    }
}

extern "C" void kernel_launch(void* const* d_in, const int* in_sizes, int n_in,
                              void* d_out, int out_size, void* d_ws, size_t ws_size,
                              hipStream_t stream) {
    const float* img   = (const float*)d_in[0];
    const int*   sizes = (const int*)d_in[1];
    const int*   offy  = (const int*)d_in[2];
    const int*   offx  = (const int*)d_in[3];
    float*       out   = (float*)d_out;

    if (ws_size >= (size_t)WS_WORDS * 4) {
        unsigned int* ws = (unsigned int*)d_ws;
        plan_kernel<<<1, 256, 0, stream>>>(sizes, offy, ws);
        cutout_row_kernel<<<NSLAB * SLAB_BLOCKS, 256, 0, stream>>>(
            img, sizes, offy, offx, ws, out);
    } else {
        make_cutouts_fallback<<<dim3(CUT_SIZE / 2, CUTN), 128, 0, stream>>>(
            img, sizes, offy, offx, out);
    }
}